// Round 6
// baseline (232.884 us; speedup 1.0000x reference)
//
#include <hip/hip_runtime.h>

// Problem constants (T=512, B=16 -> 8192 tokens), all tensors float32
#define NTOK 8192
#define CDIM 512
#define NB   8
#define RD   64
#define OD   512

typedef unsigned char  u8;
typedef unsigned int   u32;
typedef unsigned short u16;

// workspace layout (bytes)
#define WS_Q    0                       // 8192 u8
#define WS_OFF  8192                    // 257 u32 (1028 B)
#define WS_LIST 9728                    // 8192 u16 (16384 B)
#define WS_V    26112                   // 8192*64 f32 (16B aligned)
#define WS_NEED (WS_V + (size_t)NTOK * RD * 4)

// ---------------------------------------------------------------------------
// kA: 512 blocks x 512 thr, 16 tokens/block.
//  - x tile staged in LDS, XOR-8 column swizzle, read back with per-lane
//    ds_read_b128 (each lane gets its own token's data — no broadcast waste)
//  - lane = (token = lane&15, c-quarter = lane>>4); wave w owns rows
//    r = 8w..8w+7 of w1 AND logit bit w (f64, sign-critical)
//  - w1/map_w rows read as pipelined vector float4 loads (L1/L2-hot)
//  - c-quarter partials combined with deterministic shfl_xor butterfly
//  - v transposed through LDS -> coalesced float4 stores
// ---------------------------------------------------------------------------
__global__ __launch_bounds__(512) void kA(
    const float* __restrict__ x, const float* __restrict__ map_w,
    const float* __restrict__ map_b, const float* __restrict__ w1,
    u8* __restrict__ q_out, float* __restrict__ v_out,
    float* __restrict__ loss_out)
{
    const int t    = threadIdx.x;
    const int tok0 = blockIdx.x * 16;
    __shared__ float xs[16 * CDIM];     // 32 KB, swizzled
    __shared__ float vs[16 * 68];       // transpose buffer (pitch 68)
    __shared__ u32   qm[8];

    // ---- stage x tile: 2048 float4, 4 per thread, swizzled columns ----
    const float4* __restrict__ xsrc = (const float4*)(x + (size_t)tok0 * CDIM);
    #pragma unroll
    for (int u = 0; u < 4; ++u) {
        int g  = u * 512 + t;
        int r  = g >> 7, c4 = g & 127;               // row, col/4
        int col = (c4 * 4) ^ ((r & 7) << 3);         // XOR-8 swizzle
        *(float4*)(xs + r * CDIM + col) = xsrc[g];
    }
    __syncthreads();

    const int w    = t >> 6;                         // wave id 0..7 (uniform)
    const int lane = t & 63;
    const int tok  = lane & 15;
    const int ch   = lane >> 4;                      // c-quarter 0..3
    const int sw   = (tok & 7) << 3;
    const float* __restrict__ xrow = xs + tok * CDIM;
    const float* __restrict__ wrow = w1 + (size_t)(w * 8) * CDIM;
    const float* __restrict__ mrow = map_w + (size_t)w * CDIM;

    float a[8] = {0.f, 0.f, 0.f, 0.f, 0.f, 0.f, 0.f, 0.f};
    double s = 0.0;

    for (int st = 0; st < 32; ++st) {
        const int c = ch * 128 + st * 4;
        float4 xv = *(const float4*)(xrow + (c ^ sw));
        #pragma unroll
        for (int j = 0; j < 8; ++j) {
            float4 wv = *(const float4*)(wrow + (size_t)j * CDIM + c);
            a[j] += wv.x * xv.x + wv.y * xv.y + wv.z * xv.z + wv.w * xv.w;
        }
        float4 mv = *(const float4*)(mrow + c);
        s += (double)mv.x * (double)xv.x + (double)mv.y * (double)xv.y
           + (double)mv.z * (double)xv.z + (double)mv.w * (double)xv.w;
    }

    // ---- deterministic c-quarter combine (butterfly over lanes 16,32) ----
    #pragma unroll
    for (int j = 0; j < 8; ++j) {
        a[j] += __shfl_xor(a[j], 16);
        a[j] += __shfl_xor(a[j], 32);
    }
    s += __shfl_xor(s, 16);
    s += __shfl_xor(s, 32);
    s += (double)map_b[w];

    unsigned long long mask = __ballot(s > 0.0);
    if (lane == 0) qm[w] = (u32)(mask & 0xFFFFull);

    if (lane < 16) {
        #pragma unroll
        for (int j = 0; j < 8; ++j) vs[tok * 68 + w * 8 + j] = a[j];
    }
    __syncthreads();

    if (t < 16) {
        u32 q = 0;
        #pragma unroll
        for (int b = 0; b < 8; ++b) q |= ((qm[b] >> t) & 1u) << b;
        q_out[tok0 + t] = (u8)q;
    }
    if (t < 256) {                                   // coalesced v store
        int tk = t >> 4, j4 = t & 15;
        *(float4*)(v_out + (size_t)(tok0 + tk) * RD + j4 * 4) =
            *(const float4*)(vs + tk * 68 + j4 * 4);
    }
    if (blockIdx.x == 0 && t == 0) loss_out[0] = 0.0f;  // loss output = 0
}

// ---------------------------------------------------------------------------
// kSort: single block, 1024 thr. histogram -> prefix -> scatter (fused).
// ---------------------------------------------------------------------------
__global__ __launch_bounds__(1024) void kSort(
    const u8* __restrict__ q_arr, u32* __restrict__ off, u16* __restrict__ list)
{
    __shared__ u32 hist[256], curs[256], scan[256];
    const int t = threadIdx.x;
    if (t < 256) hist[t] = 0u;
    __syncthreads();
    for (int i = t; i < NTOK; i += 1024) atomicAdd(&hist[q_arr[i]], 1u);
    __syncthreads();
    if (t < 256) scan[t] = hist[t];
    __syncthreads();
    for (int d = 1; d < 256; d <<= 1) {
        u32 v = 0u;
        if (t < 256 && t >= d) v = scan[t - d];
        __syncthreads();
        if (t < 256) scan[t] += v;
        __syncthreads();
    }
    if (t < 256) {
        u32 excl = scan[t] - hist[t];
        curs[t] = excl;
        off[t]  = excl;
        if (t == 255) off[256] = scan[255];
    }
    __syncthreads();
    for (int i = t; i < NTOK; i += 1024) {
        u32 pos = atomicAdd(&curs[q_arr[i]], 1u);
        list[pos] = (u16)i;
    }
}

// ---------------------------------------------------------------------------
// kB: 512 blocks x 256 thr, block = (q = b>>1, output-half b&1). Thread owns
// output o; fused weights w21[q,o,:]+w22[255-q,o,:] in 64 VGPRs (both tables
// batch-loaded up-front); bucket list staged in LDS; 4 tokens/iteration with
// independent accumulators over pipelined vector v-row loads.
// ---------------------------------------------------------------------------
__global__ __launch_bounds__(256) void kB(
    const u16* __restrict__ list, const u32* __restrict__ off,
    const float* __restrict__ v_arr,
    const float* __restrict__ w21, const float* __restrict__ w22,
    const float* __restrict__ pwB, float* __restrict__ y)
{
    const int q  = blockIdx.x >> 1;
    const int oh = blockIdx.x & 1;
    const int t  = threadIdx.x;
    const int o  = oh * 256 + t;
    const u32 lo = off[q], hi = off[q + 1];
    const int n  = (int)(hi - lo);
    if (n == 0) return;

    __shared__ u16 ltok[NTOK];

    const float4* __restrict__ pa = (const float4*)(w21 + ((size_t)q * OD + o) * RD);
    const float4* __restrict__ pb = (const float4*)(w22 + ((size_t)(255 - q) * OD + o) * RD);
    float4 wa[16], wb[16];
    #pragma unroll
    for (int j = 0; j < 16; ++j) wa[j] = pa[j];
    #pragma unroll
    for (int j = 0; j < 16; ++j) wb[j] = pb[j];

    for (int i = t; i < n; i += 256) ltok[i] = list[lo + i];

    float4 w[16];
    #pragma unroll
    for (int j = 0; j < 16; ++j)
        w[j] = make_float4(wa[j].x + wb[j].x, wa[j].y + wb[j].y,
                           wa[j].z + wb[j].z, wa[j].w + wb[j].w);
    const float bias = pwB[o];
    __syncthreads();

    const float4* __restrict__ v4 = (const float4*)v_arr;
    for (int i = 0; i < n; i += 4) {
        const int nb = n - i;
        const int t0 = (int)ltok[i];
        const int t1 = (int)ltok[(nb > 1) ? i + 1 : i];
        const int t2 = (int)ltok[(nb > 2) ? i + 2 : i];
        const int t3 = (int)ltok[(nb > 3) ? i + 3 : i];
        const float4* __restrict__ p0 = v4 + (size_t)t0 * 16;
        const float4* __restrict__ p1 = v4 + (size_t)t1 * 16;
        const float4* __restrict__ p2 = v4 + (size_t)t2 * 16;
        const float4* __restrict__ p3 = v4 + (size_t)t3 * 16;
        float a0 = bias, a1 = bias, a2 = bias, a3 = bias;
        #pragma unroll
        for (int j = 0; j < 16; ++j) {
            float4 ww = w[j];
            float4 v0 = p0[j]; a0 += ww.x*v0.x + ww.y*v0.y + ww.z*v0.z + ww.w*v0.w;
            float4 v1 = p1[j]; a1 += ww.x*v1.x + ww.y*v1.y + ww.z*v1.z + ww.w*v1.w;
            float4 v2 = p2[j]; a2 += ww.x*v2.x + ww.y*v2.y + ww.z*v2.z + ww.w*v2.w;
            float4 v3 = p3[j]; a3 += ww.x*v3.x + ww.y*v3.y + ww.z*v3.z + ww.w*v3.w;
        }
        y[(size_t)t0 * OD + o] = a0;
        if (nb > 1) y[(size_t)t1 * OD + o] = a1;
        if (nb > 2) y[(size_t)t2 * OD + o] = a2;
        if (nb > 3) y[(size_t)t3 * OD + o] = a3;
    }
}

// ---------------------------------------------------------------------------
// Fallback (ws too small): workspace-free, one block per token.
// ---------------------------------------------------------------------------
__global__ __launch_bounds__(256) void mono(
    const float* __restrict__ x, const float* __restrict__ map_w,
    const float* __restrict__ map_b, const float* __restrict__ w1,
    const float* __restrict__ w21, const float* __restrict__ w22,
    const float* __restrict__ pwB, float* __restrict__ y)
{
    const int tok = blockIdx.x;
    const int t   = threadIdx.x;
    __shared__ float xsh[CDIM];
    __shared__ float vsh[RD];
    __shared__ int qsh;

    if (t == 0) qsh = 0;
    for (int i = t; i < CDIM; i += 256) xsh[i] = x[(size_t)tok * CDIM + i];
    __syncthreads();

    if (t < NB) {
        double a = 0.0;
        const float* mrow = map_w + (size_t)t * CDIM;
        for (int j = 0; j < CDIM; ++j) a += (double)mrow[j] * (double)xsh[j];
        a += (double)map_b[t];
        if (a > 0.0) atomicOr(&qsh, 1 << t);
    }
    if (t < RD) {
        const float* wrow = w1 + (size_t)t * CDIM;
        float acc = 0.f;
        for (int j = 0; j < CDIM; ++j) acc += wrow[j] * xsh[j];
        vsh[t] = acc;
    }
    __syncthreads();

    const int q = qsh;
    for (int o = t; o < OD; o += 256) {
        const float* pa = w21 + (size_t)q * (OD * RD) + (size_t)o * RD;
        const float* pb = w22 + (size_t)(255 - q) * (OD * RD) + (size_t)o * RD;
        float acc = pwB[o];
        for (int r = 0; r < RD; ++r) acc += (pa[r] + pb[r]) * vsh[r];
        y[(size_t)tok * OD + o] = acc;
    }
    if (tok == 0 && t == 0) y[(size_t)NTOK * OD] = 0.0f;
}

extern "C" void kernel_launch(void* const* d_in, const int* in_sizes, int n_in,
                              void* d_out, int out_size, void* d_ws, size_t ws_size,
                              hipStream_t stream) {
    const float* x     = (const float*)d_in[0];
    // d_in[1] = key: unused by the forward pass
    const float* map_w = (const float*)d_in[2];
    const float* map_b = (const float*)d_in[3];
    const float* w1    = (const float*)d_in[4];
    const float* w21   = (const float*)d_in[5];
    const float* w22   = (const float*)d_in[6];
    const float* pwB   = (const float*)d_in[7];
    float* out = (float*)d_out;

    if (ws_size >= WS_NEED) {
        char* ws = (char*)d_ws;
        u8*    q_ws   = (u8*)(ws + WS_Q);
        u32*   off    = (u32*)(ws + WS_OFF);
        u16*   list   = (u16*)(ws + WS_LIST);
        float* v_ws   = (float*)(ws + WS_V);

        kA<<<NTOK / 16, 512, 0, stream>>>(x, map_w, map_b, w1, q_ws, v_ws,
                                          out + (size_t)NTOK * OD);
        kSort<<<1, 1024, 0, stream>>>(q_ws, off, list);
        kB<<<512, 256, 0, stream>>>(list, off, v_ws, w21, w22, pwB, out);
    } else {
        mono<<<NTOK, 256, 0, stream>>>(x, map_w, map_b, w1, w21, w22, pwB, out);
    }
}

// Round 8
// 205.520 us; speedup vs baseline: 1.1331x; 1.1331x over previous
//
#include <hip/hip_runtime.h>

// Problem constants (T=512, B=16 -> 8192 tokens), all tensors float32
#define NTOK 8192
#define CDIM 512
#define NB   8
#define RD   64
#define OD   512

typedef unsigned char  u8;
typedef unsigned int   u32;
typedef unsigned short u16;

// workspace layout (bytes)
#define WS_Q    0                       // 8192 u8
#define WS_OFF  8192                    // 257 u32 (1028 B)
#define WS_LIST 9728                    // 8192 u16 (16384 B)
#define WS_V    26112                   // 8192*64 f32 (16B aligned)
#define WS_NEED (WS_V + (size_t)NTOK * RD * 4)

// ---------------------------------------------------------------------------
// kA (UNCHANGED — control)
// ---------------------------------------------------------------------------
__global__ __launch_bounds__(512) void kA(
    const float* __restrict__ x, const float* __restrict__ map_w,
    const float* __restrict__ map_b, const float* __restrict__ w1,
    u8* __restrict__ q_out, float* __restrict__ v_out,
    float* __restrict__ loss_out)
{
    const int t    = threadIdx.x;
    const int tok0 = blockIdx.x * 16;
    __shared__ float xs[16 * CDIM];     // 32 KB, swizzled
    __shared__ float vs[16 * 68];       // transpose buffer (pitch 68)
    __shared__ u32   qm[8];

    const float4* __restrict__ xsrc = (const float4*)(x + (size_t)tok0 * CDIM);
    #pragma unroll
    for (int u = 0; u < 4; ++u) {
        int g  = u * 512 + t;
        int r  = g >> 7, c4 = g & 127;               // row, col/4
        int col = (c4 * 4) ^ ((r & 7) << 3);         // XOR-8 swizzle
        *(float4*)(xs + r * CDIM + col) = xsrc[g];
    }
    __syncthreads();

    const int w    = t >> 6;                         // wave id 0..7 (uniform)
    const int lane = t & 63;
    const int tok  = lane & 15;
    const int ch   = lane >> 4;                      // c-quarter 0..3
    const int sw   = (tok & 7) << 3;
    const float* __restrict__ xrow = xs + tok * CDIM;
    const float* __restrict__ wrow = w1 + (size_t)(w * 8) * CDIM;
    const float* __restrict__ mrow = map_w + (size_t)w * CDIM;

    float a[8] = {0.f, 0.f, 0.f, 0.f, 0.f, 0.f, 0.f, 0.f};
    double s = 0.0;

    for (int st = 0; st < 32; ++st) {
        const int c = ch * 128 + st * 4;
        float4 xv = *(const float4*)(xrow + (c ^ sw));
        #pragma unroll
        for (int j = 0; j < 8; ++j) {
            float4 wv = *(const float4*)(wrow + (size_t)j * CDIM + c);
            a[j] += wv.x * xv.x + wv.y * xv.y + wv.z * xv.z + wv.w * xv.w;
        }
        float4 mv = *(const float4*)(mrow + c);
        s += (double)mv.x * (double)xv.x + (double)mv.y * (double)xv.y
           + (double)mv.z * (double)xv.z + (double)mv.w * (double)xv.w;
    }

    #pragma unroll
    for (int j = 0; j < 8; ++j) {
        a[j] += __shfl_xor(a[j], 16);
        a[j] += __shfl_xor(a[j], 32);
    }
    s += __shfl_xor(s, 16);
    s += __shfl_xor(s, 32);
    s += (double)map_b[w];

    unsigned long long mask = __ballot(s > 0.0);
    if (lane == 0) qm[w] = (u32)(mask & 0xFFFFull);

    if (lane < 16) {
        #pragma unroll
        for (int j = 0; j < 8; ++j) vs[tok * 68 + w * 8 + j] = a[j];
    }
    __syncthreads();

    if (t < 16) {
        u32 q = 0;
        #pragma unroll
        for (int b = 0; b < 8; ++b) q |= ((qm[b] >> t) & 1u) << b;
        q_out[tok0 + t] = (u8)q;
    }
    if (t < 256) {
        int tk = t >> 4, j4 = t & 15;
        *(float4*)(v_out + (size_t)(tok0 + tk) * RD + j4 * 4) =
            *(const float4*)(vs + tk * 68 + j4 * 4);
    }
    if (blockIdx.x == 0 && t == 0) loss_out[0] = 0.0f;  // loss output = 0
}

// ---------------------------------------------------------------------------
// kSort (UNCHANGED): histogram -> prefix -> scatter (fused, one block)
// ---------------------------------------------------------------------------
__global__ __launch_bounds__(1024) void kSort(
    const u8* __restrict__ q_arr, u32* __restrict__ off, u16* __restrict__ list)
{
    __shared__ u32 hist[256], curs[256], scan[256];
    const int t = threadIdx.x;
    if (t < 256) hist[t] = 0u;
    __syncthreads();
    for (int i = t; i < NTOK; i += 1024) atomicAdd(&hist[q_arr[i]], 1u);
    __syncthreads();
    if (t < 256) scan[t] = hist[t];
    __syncthreads();
    for (int d = 1; d < 256; d <<= 1) {
        u32 v = 0u;
        if (t < 256 && t >= d) v = scan[t - d];
        __syncthreads();
        if (t < 256) scan[t] += v;
        __syncthreads();
    }
    if (t < 256) {
        u32 excl = scan[t] - hist[t];
        curs[t] = excl;
        off[t]  = excl;
        if (t == 255) off[256] = scan[255];
    }
    __syncthreads();
    for (int i = t; i < NTOK; i += 1024) {
        u32 pos = atomicAdd(&curs[q_arr[i]], 1u);
        list[pos] = (u16)i;
    }
}

// ---------------------------------------------------------------------------
// kB: 2048 blocks x 64 thr (one wave). block = (q = b>>3, og = b&7).
// lane owns output o = og*64+lane: fused weights in 64 VGPRs. Bucket v-rows
// staged coalesced into LDS in <=64-token chunks. Chunk token ids go through
// LDS (ctok) — NOT __shfl: R7's shfl-from-inactive-source-lane in the ragged
// last staging iteration returned garbage (ds_bpermute reads inactive lanes
// as 0) and corrupted tail tokens. Store is guarded; trip count uniform.
// ---------------------------------------------------------------------------
__global__ __launch_bounds__(64) void kB(
    const u16* __restrict__ list, const u32* __restrict__ off,
    const float* __restrict__ v_arr,
    const float* __restrict__ w21, const float* __restrict__ w22,
    const float* __restrict__ pwB, float* __restrict__ y)
{
    const int q    = blockIdx.x >> 3;
    const int og   = blockIdx.x & 7;
    const int lane = threadIdx.x;                    // 0..63
    const int o    = og * 64 + lane;
    const u32 lo   = off[q];
    const int n    = (int)(off[q + 1] - lo);
    if (n == 0) return;

    __shared__ float vsl[64 * RD];                   // 16 KB: staged v rows
    __shared__ u16   ctok[64];                       // chunk token ids

    // fused weight row for output o (64 f32 in VGPRs)
    const float4* __restrict__ pa = (const float4*)(w21 + ((size_t)q * OD + o) * RD);
    const float4* __restrict__ pb = (const float4*)(w22 + ((size_t)(255 - q) * OD + o) * RD);
    float4 w[16];
    #pragma unroll
    for (int j = 0; j < 16; ++j) {
        float4 a = pa[j], b = pb[j];
        w[j] = make_float4(a.x + b.x, a.y + b.y, a.z + b.z, a.w + b.w);
    }
    const float bias = pwB[o];
    const float4* __restrict__ v4 = (const float4*)v_arr;

    for (int base = 0; base < n; base += 64) {
        const int nc = min(64, n - base);
        ctok[lane] = list[lo + base + min(lane, nc - 1)];
        __syncthreads();
        // stage v rows coalesced: guarded, uniform trip count
        const int tot = nc * 16;
        for (int i0 = 0; i0 < tot; i0 += 64) {
            const int i = i0 + lane;
            if (i < tot) {
                const int tok = (int)ctok[i >> 4];
                *(float4*)(vsl + i * 4) = v4[(size_t)tok * 16 + (i & 15)];
            }
        }
        __syncthreads();
        for (int c = 0; c < nc; ++c) {
            const float* vp = vsl + c * RD;
            float a0 = 0.f, a1 = 0.f, a2 = 0.f, a3 = 0.f;
            #pragma unroll
            for (int j = 0; j < 16; j += 4) {
                float4 v0 = *(const float4*)(vp + (j + 0) * 4);
                float4 v1 = *(const float4*)(vp + (j + 1) * 4);
                float4 v2 = *(const float4*)(vp + (j + 2) * 4);
                float4 v3 = *(const float4*)(vp + (j + 3) * 4);
                a0 += w[j+0].x*v0.x + w[j+0].y*v0.y + w[j+0].z*v0.z + w[j+0].w*v0.w;
                a1 += w[j+1].x*v1.x + w[j+1].y*v1.y + w[j+1].z*v1.z + w[j+1].w*v1.w;
                a2 += w[j+2].x*v2.x + w[j+2].y*v2.y + w[j+2].z*v2.z + w[j+2].w*v2.w;
                a3 += w[j+3].x*v3.x + w[j+3].y*v3.y + w[j+3].z*v3.z + w[j+3].w*v3.w;
            }
            const int tok = (int)ctok[c];
            y[(size_t)tok * OD + o] = bias + (a0 + a1) + (a2 + a3);
        }
        __syncthreads();
    }
}

// ---------------------------------------------------------------------------
// Fallback (ws too small): workspace-free, one block per token.
// ---------------------------------------------------------------------------
__global__ __launch_bounds__(256) void mono(
    const float* __restrict__ x, const float* __restrict__ map_w,
    const float* __restrict__ map_b, const float* __restrict__ w1,
    const float* __restrict__ w21, const float* __restrict__ w22,
    const float* __restrict__ pwB, float* __restrict__ y)
{
    const int tok = blockIdx.x;
    const int t   = threadIdx.x;
    __shared__ float xsh[CDIM];
    __shared__ float vsh[RD];
    __shared__ int qsh;

    if (t == 0) qsh = 0;
    for (int i = t; i < CDIM; i += 256) xsh[i] = x[(size_t)tok * CDIM + i];
    __syncthreads();

    if (t < NB) {
        double a = 0.0;
        const float* mrow = map_w + (size_t)t * CDIM;
        for (int j = 0; j < CDIM; ++j) a += (double)mrow[j] * (double)xsh[j];
        a += (double)map_b[t];
        if (a > 0.0) atomicOr(&qsh, 1 << t);
    }
    if (t < RD) {
        const float* wrow = w1 + (size_t)t * CDIM;
        float acc = 0.f;
        for (int j = 0; j < CDIM; ++j) acc += wrow[j] * xsh[j];
        vsh[t] = acc;
    }
    __syncthreads();

    const int q = qsh;
    for (int o = t; o < OD; o += 256) {
        const float* pa = w21 + (size_t)q * (OD * RD) + (size_t)o * RD;
        const float* pb = w22 + (size_t)(255 - q) * (OD * RD) + (size_t)o * RD;
        float acc = pwB[o];
        for (int r = 0; r < RD; ++r) acc += (pa[r] + pb[r]) * vsh[r];
        y[(size_t)tok * OD + o] = acc;
    }
    if (tok == 0 && t == 0) y[(size_t)NTOK * OD] = 0.0f;
}

extern "C" void kernel_launch(void* const* d_in, const int* in_sizes, int n_in,
                              void* d_out, int out_size, void* d_ws, size_t ws_size,
                              hipStream_t stream) {
    const float* x     = (const float*)d_in[0];
    // d_in[1] = key: unused by the forward pass
    const float* map_w = (const float*)d_in[2];
    const float* map_b = (const float*)d_in[3];
    const float* w1    = (const float*)d_in[4];
    const float* w21   = (const float*)d_in[5];
    const float* w22   = (const float*)d_in[6];
    const float* pwB   = (const float*)d_in[7];
    float* out = (float*)d_out;

    if (ws_size >= WS_NEED) {
        char* ws = (char*)d_ws;
        u8*    q_ws   = (u8*)(ws + WS_Q);
        u32*   off    = (u32*)(ws + WS_OFF);
        u16*   list   = (u16*)(ws + WS_LIST);
        float* v_ws   = (float*)(ws + WS_V);

        kA<<<NTOK / 16, 512, 0, stream>>>(x, map_w, map_b, w1, q_ws, v_ws,
                                          out + (size_t)NTOK * OD);
        kSort<<<1, 1024, 0, stream>>>(q_ws, off, list);
        kB<<<2048, 64, 0, stream>>>(list, off, v_ws, w21, w22, pwB, out);
    } else {
        mono<<<NTOK, 256, 0, stream>>>(x, map_w, map_b, w1, w21, w22, pwB, out);
    }
}